// Round 1
// baseline (49.805 us; speedup 1.0000x reference)
//
#include <hip/hip_runtime.h>
#include <math.h>

#define BSZ   65536
#define INP   16
#define HL    10
#define NL    3
#define TT    200
#define NPOP  8600000.0f

__global__ __launch_bounds__(256) void sir_kernel(
    const float* __restrict__ data,   // B x IN
    const float* __restrict__ times,  // T
    const float* __restrict__ W0,     // 3 x HL x IN
    const float* __restrict__ b0,     // 3 x HL
    const float* __restrict__ Wh,     // 3 x NL x HL x HL
    const float* __restrict__ bh,     // 3 x NL x HL
    const float* __restrict__ Wo,     // 3 x 1 x HL
    const float* __restrict__ bo,     // 3 x 1
    float* __restrict__ out)          // T x B
{
    __shared__ float sW0[3 * HL * INP];
    __shared__ float sb0[3 * HL];
    __shared__ float sWh[3 * NL * HL * HL];
    __shared__ float sbh[3 * NL * HL];
    __shared__ float sWo[3 * HL];
    __shared__ float sbo[3];
    __shared__ float st[TT];

    const int tid = threadIdx.x;
    for (int i = tid; i < 3 * HL * INP;     i += 256) sW0[i] = W0[i];
    for (int i = tid; i < 3 * HL;           i += 256) sb0[i] = b0[i];
    for (int i = tid; i < 3 * NL * HL * HL; i += 256) sWh[i] = Wh[i];
    for (int i = tid; i < 3 * NL * HL;      i += 256) sbh[i] = bh[i];
    for (int i = tid; i < 3 * HL;           i += 256) sWo[i] = Wo[i];
    if (tid < 3) sbo[tid] = bo[tid];
    for (int i = tid; i < TT;               i += 256) st[i] = times[i];
    __syncthreads();

    const int b = blockIdx.x * 256 + tid;

    // ---- load input row (64B/lane, coalesced as 4x float4) ----
    float x[INP];
    const float4* xin = reinterpret_cast<const float4*>(data + (size_t)b * INP);
    #pragma unroll
    for (int q = 0; q < INP / 4; ++q) {
        float4 v = xin[q];
        x[q * 4 + 0] = v.x; x[q * 4 + 1] = v.y;
        x[q * 4 + 2] = v.z; x[q * 4 + 3] = v.w;
    }

    // ---- three parameter nets ----
    float vals[3];
    #pragma unroll 1
    for (int n = 0; n < 3; ++n) {
        float h[HL];
        #pragma unroll
        for (int k = 0; k < HL; ++k) {
            float acc = sb0[n * HL + k];
            #pragma unroll
            for (int i = 0; i < INP; ++i)
                acc = fmaf(x[i], sW0[(n * HL + k) * INP + i], acc);
            h[k] = tanhf(acc);
        }
        #pragma unroll 1
        for (int l = 0; l < NL; ++l) {
            float h2[HL];
            #pragma unroll
            for (int k = 0; k < HL; ++k) {
                float acc = sbh[(n * NL + l) * HL + k];
                #pragma unroll
                for (int i = 0; i < HL; ++i)
                    acc = fmaf(h[i], sWh[((n * NL + l) * HL + k) * HL + i], acc);
                h2[k] = tanhf(acc);
            }
            #pragma unroll
            for (int k = 0; k < HL; ++k) h[k] = h2[k];
        }
        float acc = sbo[n];
        #pragma unroll
        for (int i = 0; i < HL; ++i)
            acc = fmaf(h[i], sWo[n * HL + i], acc);
        // stable softplus: max(x,0) + log1p(exp(-|x|))
        vals[n] = fmaxf(acc, 0.0f) + log1pf(expf(-fabsf(acc)));
    }

    const float gamma = vals[0];
    const float beta  = vals[1];
    const float I0    = vals[2];

    float S = NPOP - I0;
    float I = I0;
    const float bn = beta * (1.0f / NPOP);   // beta/NPOP folded

    out[b] = I;   // t = 0 (x0's I compartment)

    // ---- RK4 over 199 steps ----
    for (int t = 0; t < TT - 1; ++t) {
        const float dt  = st[t + 1] - st[t];
        const float hdt = 0.5f * dt;

        float flux, rec;
        // k1
        flux = bn * S * I;  rec = gamma * I;
        const float k1S = -flux, k1I = flux - rec;
        // k2
        float aS = fmaf(hdt, k1S, S), aI = fmaf(hdt, k1I, I);
        flux = bn * aS * aI;  rec = gamma * aI;
        const float k2S = -flux, k2I = flux - rec;
        // k3
        aS = fmaf(hdt, k2S, S);  aI = fmaf(hdt, k2I, I);
        flux = bn * aS * aI;  rec = gamma * aI;
        const float k3S = -flux, k3I = flux - rec;
        // k4
        aS = fmaf(dt, k3S, S);  aI = fmaf(dt, k3I, I);
        flux = bn * aS * aI;  rec = gamma * aI;
        const float k4S = -flux, k4I = flux - rec;

        const float c = dt * (1.0f / 6.0f);
        S = fmaf(c, k1S + 2.0f * k2S + 2.0f * k3S + k4S, S);
        I = fmaf(c, k1I + 2.0f * k2I + 2.0f * k3I + k4I, I);

        out[(size_t)(t + 1) * BSZ + b] = I;
    }
}

extern "C" void kernel_launch(void* const* d_in, const int* in_sizes, int n_in,
                              void* d_out, int out_size, void* d_ws, size_t ws_size,
                              hipStream_t stream) {
    const float* data  = (const float*)d_in[0];
    const float* times = (const float*)d_in[1];
    const float* W0    = (const float*)d_in[2];
    const float* b0    = (const float*)d_in[3];
    const float* Wh    = (const float*)d_in[4];
    const float* bh    = (const float*)d_in[5];
    const float* Wo    = (const float*)d_in[6];
    const float* bo    = (const float*)d_in[7];
    float* out = (float*)d_out;

    sir_kernel<<<BSZ / 256, 256, 0, stream>>>(data, times, W0, b0, Wh, bh, Wo, bo, out);
}